// Round 16
// baseline (298.397 us; speedup 1.0000x reference)
//
#include <hip/hip_runtime.h>
#include <hip/hip_bf16.h>

typedef _Float16 f16;
typedef _Float16 f16x4 __attribute__((ext_vector_type(4)));
typedef _Float16 f16x8 __attribute__((ext_vector_type(8)));
typedef float    f32x4 __attribute__((ext_vector_type(4)));

static __device__ __forceinline__ float bf2f(__hip_bfloat16 x) { return __bfloat162float(x); }
// dual-dtype float load/store: f32flag=1 -> float*, else bf16*
static __device__ __forceinline__ float ldf(const void* p, long i, int f32flag) {
    return f32flag ? ((const float*)p)[i] : bf2f(((const __hip_bfloat16*)p)[i]);
}
static __device__ __forceinline__ void stf(void* p, long i, int f32flag, float v) {
    if (f32flag) ((float*)p)[i] = v;
    else ((__hip_bfloat16*)p)[i] = __float2bfloat16(v);
}
// async global->LDS, 16B per lane; LDS dest is wave-uniform base + lane*16
static __device__ __forceinline__ void gl2lds16(const f16* g, f16* l) {
    __builtin_amdgcn_global_load_lds(
        (const __attribute__((address_space(1))) unsigned int*)(const void*)g,
        (__attribute__((address_space(3))) unsigned int*)(void*)l, 16, 0, 0);
}

// ---------------- workspace layout (bytes) ----------------
// Re-associated + merged pipeline:
//   LF = feat @ [attn_w^T | Wc1 | Wc2]  (32000 x 1280, ld 1280)
//        cols 0..1023 = logits (999 real); 1024..1151 (F1) bypass LF and are
//        written TRANSPOSED straight into F1T by the GEMM epilogue; 1152..1279 = F2
//   out = softmax-scatter(LF[:, :1024]) @ F1T + F2 + bias + anchors
#define OFF_LF     0L                               // LF: 32000 x 1280 f16
#define SZ_LF      (32000L * 1280 * 2)
#define OFF_FEAT   (OFF_LF + SZ_LF)                 // feat: 32000 x 768 f16
#define SZ_FEAT    (32000L * 768 * 2)
#define OFF_AWT    (OFF_FEAT + SZ_FEAT)             // attn_w^T: 1024 x 768 f16 (rows>=999 zero)
#define SZ_AWT     (1024L * 768 * 2)
#define OFF_WCT    (OFF_AWT + SZ_AWT)               // Wc2^T: 256 x 768 f16 — MUST follow awT
#define SZ_WCT     (256L * 768 * 2)                 // (B' = awT..wcT2 = 1280 contiguous rows)
#define OFF_BIAS   (OFF_WCT + SZ_WCT)               // f32[128]
#define OFF_AB     (OFF_BIAS + 512)                 // attn_b as f32[1024]
#define OFF_FLAG   (OFF_AB + 4096)                  // int flags[2]
#define OFF_F1T    (OFF_FLAG + 64)                  // F1^T per batch: 32 x 128 x 1024 f16
#define SZ_F1T     (32L * 128 * 1024 * 2)
#define NEED_A     (OFF_F1T + SZ_F1T)               // ~141 MB

// ---------------- front: inline detect + build_feat + weight packing (one dispatch) ----------------
// Detection (dtype of fv / format of mask) is recomputed locally by EVERY block from
// the same fixed global sample (deterministic, ~24 KB L2-hot reads). Block 2047
// publishes flags for GEMMS. Third branch also zero-fills F1T pad columns
// (m=1000..1023 of each of 32x128 rows) so the GEMM's direct-F1T write needs no pad.
// grid 2048: [0,512) feat gather; [512,1280) awT transpose; [1280,2048) wcT2/bias/abf32/F1T-pad
__global__ __launch_bounds__(256) void front_kernel(
    const void* __restrict__ fv, const int* __restrict__ x_idx,
    const void* __restrict__ maskp,
    int xstride, int mstride, int mwords, f16* __restrict__ feat,
    const void* __restrict__ attn_w,
    const void* __restrict__ cls_w, const void* __restrict__ cls_b,
    const void* __restrict__ reg_w, const void* __restrict__ reg_b,
    const void* __restrict__ attn_b,
    f16* __restrict__ awT, f16* __restrict__ wcT,
    float* __restrict__ biasc, float* __restrict__ abf32,
    int* __restrict__ flags, f16* __restrict__ F1T)
{
    __shared__ int s_cnt, s_bits;
    int bid = blockIdx.x;
    int t = threadIdx.x;
    if (t == 0) { s_cnt = 0; s_bits = 0; }
    __syncthreads();
    {
        const unsigned int* fvw = (const unsigned int*)fv;
        const unsigned int* mw  = (const unsigned int*)maskp;
        int c = 0;
        for (int k = t; k < 2048; k += 256) {
            unsigned int wv = fvw[k];
            unsigned int h0 = wv & 0xffffu, h1 = wv >> 16;
            unsigned int e0 = (h0 >> 7) & 0xffu, e1 = (h1 >> 7) & 0xffu;
            c += (h0 == 0u || (e0 >= 100u && e0 <= 135u)) ? 1 : 0;
            c += (h1 == 0u || (e1 >= 100u && e1 <= 135u)) ? 1 : 0;
        }
        atomicAdd(&s_cnt, c);
        int lb = 0;
        for (int k = t; k < mwords; k += 256) {
            unsigned int wv = mw[k];
            if (wv > 1u) lb |= 1;
            if ((k & 1) && wv != 0u) lb |= 2;
            unsigned int lo = wv & 0xffffu, hi = wv >> 16;
            if (!((lo == 0u || lo == 0x3f80u) && (hi == 0u || hi == 0x3f80u))) lb |= 4;
            if (lo == 0x3f80u) lb |= 8;
        }
        if (lb) atomicOr(&s_bits, lb);
    }
    __syncthreads();
    int db = s_bits, fm;
    if (!(db & 1))      fm = (db & 2) ? 0 : 3;
    else if (!(db & 4)) fm = (db & 8) ? 2 : 4;
    else                fm = 1;
    int isf = (s_cnt < 3900) ? 1 : 0;
    if (bid == 2047 && t == 0) { flags[0] = fm; flags[1] = isf; }   // for GEMMS epilogue

    if (bid < 512) {
        __shared__ f16 sfv[15360];                  // [(c*12+h)*20 + x]
        __shared__ int sx[756];
        __shared__ unsigned char sm[756];
        int b = bid >> 4, n0 = (bid & 15) * 63;
        int rows = min(63, 1000 - n0);
        if (isf) {                                  // f32: 3840 float4
            const float4* src = (const float4*)fv + (long)b * 3840;
            for (int k = t; k < 3840; k += 256) {
                float4 v = src[k];
                f16x4 h; h[0] = (f16)v.x; h[1] = (f16)v.y; h[2] = (f16)v.z; h[3] = (f16)v.w;
                *(f16x4*)&sfv[k * 4] = h;
            }
        } else {                                    // bf16: 1920 uint4
            const uint4* src = (const uint4*)fv + (long)b * 1920;
            for (int k = t; k < 1920; k += 256) {
                uint4 v = src[k];
                unsigned int wv[4] = {v.x, v.y, v.z, v.w};
                f16x8 h;
                #pragma unroll
                for (int j = 0; j < 4; j++) {
                    h[2 * j]     = (f16)__uint_as_float((wv[j] & 0xffffu) << 16);
                    h[2 * j + 1] = (f16)__uint_as_float(wv[j] & 0xffff0000u);
                }
                *(f16x8*)&sfv[k * 8] = h;
            }
        }
        for (int k = t; k < rows * 12; k += 256) {
            int n = k / 12, h = k - n * 12;
            sx[k] = x_idx[(long)(n0 + n) * xstride + h];
            long mb = (long)(n0 + n) * mstride + h;
            int mv;
            if (fm == 0)      mv = ((const int*)maskp)[mb] != 0;
            else if (fm == 1) mv = ((const unsigned char*)maskp)[mb] != 0;
            else if (fm == 2) mv = ((const unsigned short*)maskp)[mb] != 0;
            else if (fm == 3) mv = ((const int*)maskp)[mb * 2] != 0;
            else              mv = ((const unsigned int*)maskp)[mb] != 0;
            sm[k] = (unsigned char)mv;
        }
        __syncthreads();
        for (int q = t; q < rows * 192; q += 256) {
            int n = q / 192, r = q - n * 192;
            int e0 = r * 4;
            f16x4 v;
            #pragma unroll
            for (int j = 0; j < 4; j++) {
                int e = e0 + j;
                int h = e % 12;
                int kk = n * 12 + h;
                v[j] = sm[kk] ? (f16)0.f : sfv[e * 20 + sx[kk]];
            }
            *(f16x4*)(feat + ((long)(b * 1000 + n0 + n)) * 768 + e0) = v;
        }
    } else if (bid < 1280) {
        // attn_w (768 x 999, ld 999) -> awT (1024 x 768, ld 768), rows>=999 zero
        __shared__ f16 tile[32][33];
        int tid = bid - 512;
        int c0 = (tid % 32) * 32, r0 = (tid / 32) * 32;    // c: 0..1023, r: 0..767
        int tx = t & 31, ty = t >> 5;
        #pragma unroll
        for (int i = ty; i < 32; i += 8) {
            int r = r0 + i, c = c0 + tx;
            float v = 0.f;
            if (r < 768 && c < 999) v = ldf(attn_w, (long)r * 999 + c, isf);
            tile[i][tx] = (f16)v;
        }
        __syncthreads();
        #pragma unroll
        for (int i = ty; i < 32; i += 8) {
            int oc = c0 + i, orw = r0 + tx;
            awT[(long)oc * 768 + orw] = tile[tx][i];
        }
    } else {
        // wcT2 [256 x 768]: row c<128 -> Wc[k][c] (att part, W rows 0..767);
        //                   row c>=128 -> Wc[768+k][c-128] (feat part)
        int idx = (bid - 1280) * 256 + t;           // 256*768 = 196608
        if (idx < 256 * 768) {
            int c = idx / 768, k = idx - c * 768;
            int wrow = (c < 128) ? k : 768 + k;
            int wcol = (c < 128) ? c : c - 128;
            float v = 0.f;
            if (wcol < 2)       v = ldf(cls_w, (long)wrow * 2 + wcol, isf);
            else if (wcol < 75) v = ldf(reg_w, (long)wrow * 73 + (wcol - 2), isf);
            wcT[idx] = (f16)v;                       // wcT2[c][k], ld 768
        }
        if (idx < 75)
            biasc[idx] = (idx < 2) ? ldf(cls_b, idx, isf) : ldf(reg_b, idx - 2, isf);
        if (idx < 1024)
            abf32[idx] = (idx < 999) ? ldf(attn_b, idx, isf) : 0.f;
        if (idx < 98304) {                           // F1T pad: m=1000..1023 each row
            int b2 = idx / 3072;                     // batch (32)
            int rem = idx - b2 * 3072;
            int n2 = rem / 24, j2 = rem - n2 * 24;   // row (128) x pad col (24)
            F1T[(long)b2 * 131072 + (long)n2 * 1024 + 1000 + j2] = (f16)0.f;
        }
    }
}

// ---------------- post: softmax-scatter only (transpose now fused into GEMM epilogue) ----------------
// One LF row (b,i), cols 0..1023: softmax + position-scatter in place. grid 32000.
__global__ __launch_bounds__(256) void post_kernel(
    f16* __restrict__ buf, const float* __restrict__ abf32)
{
    int bid = blockIdx.x;
    int t = threadIdx.x;
    int i = bid % 1000, b = bid / 1000;
    f16* row = buf + ((long)(b * 1000 + i)) * 1280;
    __shared__ float red[8];
    __shared__ float epv[256];
    int k0 = t * 4;
    f16x4 rv = *(const f16x4*)(row + k0);            // all reads before any write
    float4 ab = *(const float4*)(abf32 + k0);
    float abv[4] = {ab.x, ab.y, ab.z, ab.w};
    float v[4];
    float lmax = -3.4e38f;
    #pragma unroll
    for (int j = 0; j < 4; j++) {
        int k = k0 + j;
        float x = (k < 999) ? (float)rv[j] + abv[j] : -3.4e38f;
        v[j] = x;
        lmax = fmaxf(lmax, x);
    }
    #pragma unroll
    for (int o = 32; o > 0; o >>= 1) lmax = fmaxf(lmax, __shfl_down(lmax, o, 64));
    if ((t & 63) == 0) red[t >> 6] = lmax;
    __syncthreads();
    float gmax = fmaxf(fmaxf(red[0], red[1]), fmaxf(red[2], red[3]));
    float e[4];
    float lsum = 0.f;
    #pragma unroll
    for (int j = 0; j < 4; j++) {
        int k = k0 + j;
        float x = (k < 999) ? __expf(v[j] - gmax) : 0.f;
        e[j] = x;
        lsum += x;
    }
    epv[t] = e[3];
    #pragma unroll
    for (int o = 32; o > 0; o >>= 1) lsum += __shfl_down(lsum, o, 64);
    if ((t & 63) == 0) red[4 + (t >> 6)] = lsum;
    __syncthreads();                                 // also covers epv writes
    float inv = 1.f / (red[4] + red[5] + red[6] + red[7]);
    f16x4 outv;
    if (k0 >= 1000) {                                // tail: all zeros
        #pragma unroll
        for (int j = 0; j < 4; j++) outv[j] = (f16)0.f;
    } else if (k0 + 3 < i) {                         // all p < i: own e's
        #pragma unroll
        for (int j = 0; j < 4; j++) outv[j] = (f16)(e[j] * inv);
    } else if (k0 > i) {                             // all p > i: shift by one
        float ep = epv[t - 1];                       // t>=1 guaranteed (k0>i>=0)
        outv[0] = (f16)(ep * inv);
        #pragma unroll
        for (int j = 1; j < 4; j++) outv[j] = (f16)(e[j - 1] * inv);
    } else {                                         // straddle: i in [k0, k0+3]
        #pragma unroll
        for (int j = 0; j < 4; j++) {
            int p = k0 + j;
            float s = (p == i) ? 0.f : ((p < i) ? e[j] : e[j - 1 < 0 ? 0 : j - 1]);
            if (p > i) s = e[j - 1];                 // p>i implies j>=1 here
            outv[j] = (f16)(s * inv);
        }
    }
    *(f16x4*)(row + k0) = outv;
}

// ---------------- 8-phase 256x256 MFMA GEMM (T2+T3+T4+T5) ----------------
// 512 thr = 8 waves (2M x 4N), per-wave 128x64 out, BK=64, dbuf LDS 128 KiB.
// MERGED GEMM: C = feat @ [awT | wcT2] (N=1280 = 5 tiles). Epilogue routes
// cols 1024..1151 (F1) TRANSPOSED into F1T[batch][col-1024][m%1000]; other
// cols go to LF (ld 1280). Value path identical (same f16 rounding point).
#define SB8   __builtin_amdgcn_sched_barrier(0)
#define BAR8  __builtin_amdgcn_s_barrier()
#define LGKM0 do { asm volatile("s_waitcnt lgkmcnt(0)" ::: "memory"); __builtin_amdgcn_sched_barrier(0); } while (0)
#define VM4   asm volatile("s_waitcnt vmcnt(4)" ::: "memory")

__global__ __launch_bounds__(512, 2) void gemm8p_kernel(
    const f16* __restrict__ A, int lda,
    const f16* __restrict__ Bt, int ldb,
    f16* __restrict__ C, int ldc,
    int M, int MT, int NT, int KT,
    long sA, long sB, long sC,
    f16* __restrict__ F1T)
{
    __shared__ __align__(16) f16 As[2][16384];
    __shared__ __align__(16) f16 Bs[2][16384];
    int t = threadIdx.x;
    int nwg = gridDim.x;
    int orig = blockIdx.x;
    int xcd = orig & 7, lin = orig >> 3;
    int q8 = nwg >> 3, r8 = nwg & 7;                 // bijective XCD swizzle (m204)
    int wgid = (xcd < r8 ? xcd * (q8 + 1) : r8 * (q8 + 1) + (xcd - r8) * q8) + lin;
    int per_b = MT * NT;
    int bz = wgid / per_b;
    int rem = wgid - bz * per_b;
    int mt = rem / NT, nt = rem - mt * NT;
    int m0 = mt * 256, n0 = nt * 256;
    A  += (long)bz * sA;
    Bt += (long)bz * sB;
    C  += (long)bz * sC;
    int w = t >> 6, lane = t & 63;
    int wm = (w >> 2) * 128, wn = (w & 3) * 64;
    int lr = lane & 15, lq = lane >> 4;
    int row0 = t >> 3, slot = t & 7;
    int csw = slot ^ (row0 & 7);                     // pre-swizzled global source

    f32x4 acc[8][4];
    const f32x4 z4 = {0.f, 0.f, 0.f, 0.f};
    #pragma unroll
    for (int i = 0; i < 8; i++)
        #pragma unroll
        for (int j = 0; j < 4; j++) acc[i][j] = z4;

    f16x8 a_[2][2], b_[4][2];

#define STAGE_A8(kt, h, buf) do { \
    int ktc = (kt) < KT ? (kt) : KT - 1; \
    const f16* gp = A + (long)(m0 + (h) * 128 + row0) * lda + ktc * 64 + csw * 8; \
    gl2lds16(gp,                  &As[buf][(h) * 8192 + w * 512]); \
    gl2lds16(gp + 64 * (long)lda, &As[buf][(h) * 8192 + 4096 + w * 512]); \
} while (0)
#define STAGE_B8(kt, h, buf) do { \
    int ktc = (kt) < KT ? (kt) : KT - 1; \
    const f16* gp = Bt + (long)(n0 + (h) * 128 + row0) * ldb + ktc * 64 + csw * 8; \
    gl2lds16(gp,                  &Bs[buf][(h) * 8192 + w * 512]); \
    gl2lds16(gp + 64 * (long)ldb, &Bs[buf][(h) * 8192 + 4096 + w * 512]); \
} while (0)
#define RD_B8(buf) { \
    _Pragma("unroll") for (int n = 0; n < 4; n++) { \
        int r = wn + n * 16 + lr; int rb = r * 64; int x7 = r & 7; \
        _Pragma("unroll") for (int ks = 0; ks < 2; ks++) { \
            int cc = (lq + ks * 4) ^ x7; \
            b_[n][ks] = *(const f16x8*)&Bs[buf][rb + cc * 8]; } } }
#define RD_A8(q, buf) { \
    _Pragma("unroll") for (int m2 = 0; m2 < 2; m2++) { \
        int r = wm + ((q) * 2 + m2) * 16 + lr; int rb = r * 64; int x7 = r & 7; \
        _Pragma("unroll") for (int ks = 0; ks < 2; ks++) { \
            int cc = (lq + ks * 4) ^ x7; \
            a_[m2][ks] = *(const f16x8*)&As[buf][rb + cc * 8]; } } }
#define MFMA16(q) { \
    __builtin_amdgcn_s_setprio(1); \
    _Pragma("unroll") for (int ks = 0; ks < 2; ks++) \
    _Pragma("unroll") for (int m2 = 0; m2 < 2; m2++) \
    _Pragma("unroll") for (int n = 0; n < 4; n++) \
        acc[(q) * 2 + m2][n] = __builtin_amdgcn_mfma_f32_16x16x32_f16( \
            a_[m2][ks], b_[n][ks], acc[(q) * 2 + m2][n], 0, 0, 0); \
    __builtin_amdgcn_s_setprio(0); }

    // prologue: B(0),A(0) -> buf0; B(1) -> buf1; wait oldest 8, keep B(1) in flight
    STAGE_B8(0, 0, 0); STAGE_B8(0, 1, 0);
    STAGE_A8(0, 0, 0); STAGE_A8(0, 1, 0);
    STAGE_B8(1, 0, 1); STAGE_B8(1, 1, 1);
    VM4;
    BAR8;

    int NIT = KT >> 1;
    for (int it = 0; it < NIT; it++) {
        int t0 = 2 * it, t1 = t0 + 1;
        SB8; RD_B8(0); RD_A8(0, 0); STAGE_A8(t1, 0, 1);
        BAR8; LGKM0; MFMA16(0); BAR8;
        SB8; RD_A8(1, 0); STAGE_A8(t1, 1, 1);
        BAR8; LGKM0; MFMA16(1); BAR8;
        SB8; RD_A8(2, 0); STAGE_B8(t0 + 2, 0, 0);
        BAR8; LGKM0; MFMA16(2); BAR8;
        SB8; RD_A8(3, 0); STAGE_B8(t0 + 2, 1, 0);
        BAR8; LGKM0; MFMA16(3); VM4; BAR8;
        SB8; RD_B8(1); RD_A8(0, 1); STAGE_A8(t0 + 2, 0, 0);
        BAR8; LGKM0; MFMA16(0); BAR8;
        SB8; RD_A8(1, 1); STAGE_A8(t0 + 2, 1, 0);
        BAR8; LGKM0; MFMA16(1); BAR8;
        SB8; RD_A8(2, 1); STAGE_B8(t1 + 2, 0, 1);
        BAR8; LGKM0; MFMA16(2); BAR8;
        SB8; RD_A8(3, 1); STAGE_B8(t1 + 2, 1, 1);
        BAR8; LGKM0; MFMA16(3); VM4; BAR8;
    }

    // epilogue: C/D layout col=lane&15, row=(lane>>4)*4+reg.
    // F1 columns (1024..1151) are written transposed into F1T; rest to C.
    #pragma unroll
    for (int m = 0; m < 8; m++)
        #pragma unroll
        for (int n = 0; n < 4; n++)
            #pragma unroll
            for (int r = 0; r < 4; r++) {
                int gm = m0 + wm + m * 16 + lq * 4 + r;
                int gn = n0 + wn + n * 16 + lr;
                if (gm < M) {
                    f16 val = (f16)acc[m][n][r];
                    if (gn >= 1024 && gn < 1152) {
                        int batch = gm / 1000;
                        int mm = gm - batch * 1000;
                        F1T[(long)batch * 131072 + (long)(gn - 1024) * 1024 + mm] = val;
                    } else {
                        C[(long)gm * ldc + gn] = val;
                    }
                }
            }
#undef STAGE_A8
#undef STAGE_B8
#undef RD_B8
#undef RD_A8
#undef MFMA16
}

// ---------------- MFMA GEMM (GEMMS: BG path, A-only LDS, fused epilogue) ----------------
enum { OUT_F16 = 0, OUT_FINAL = 1 };

template<int MODE, bool CAT, bool BKM, int TM, int TN, int BK, int SWZ, bool BG>
__global__ __launch_bounds__(256, 2) void gemm_kernel(
    const f16* __restrict__ A, const f16* __restrict__ A2, int lda,
    const f16* __restrict__ Bt, int ldb,
    void* __restrict__ Cout, int ldc,
    int M, int Nc, int K,
    long sA, long sB, long sC,
    const float* __restrict__ bias, const void* __restrict__ anchors,
    const int* __restrict__ flags, const f16* __restrict__ F2c)
{
    int t = threadIdx.x;
    int bx, by, bz;
    bx = blockIdx.x; by = blockIdx.y; bz = blockIdx.z;

    int m0 = by * TM, n0 = bx * TN;
    int z = bz;
    A  += (long)z * sA;
    if (CAT) A2 += (long)z * sA;
    Bt += (long)z * sB;
    int w = t >> 6, lane = t & 63;
    constexpr int NJ = (TM == 128 && TN == 256) ? 8 : ((TN == 256) ? 4 : ((TM == 128) ? 4 : 2));
    int wm = (TM == 128) ? (w & 1) * 64 : 0;
    int wn;
    if constexpr (TM == 128 && TN == 256) wn = (w >> 1) * 128;
    else if constexpr (TN == 256)         wn = w * 64;
    else if constexpr (TM == 128)         wn = (w >> 1) * 64;
    else                                  wn = w * 32;

    int lr = lane & 15, lq = lane >> 4;

    const f32x4 zero4 = {0.f, 0.f, 0.f, 0.f};
    f32x4 acc[4][NJ];
    #pragma unroll
    for (int i = 0; i < 4; i++)
        #pragma unroll
        for (int j = 0; j < NJ; j++) acc[i][j] = zero4;

    if constexpr (BG) {
        // A staged to LDS; B fragments straight from global (B must be L2-hot & row-padded)
        constexpr int CH  = BK / 8;
        constexpr int AI  = TM * BK / 2048;
        constexpr int RPO = 2048 / BK;
        __shared__ __align__(16) f16 As[TM * BK];
        int row0 = t / CH, slot = t % CH;
        int csw = slot ^ (row0 & (CH - 1));
        long aoffB = (long)(m0 + row0) * lda + csw * 8;
        for (int k0 = 0; k0 < K; k0 += BK) {
            const f16* Ak = A; int kk = k0;
            if (CAT && k0 >= 768) { Ak = A2; kk = k0 - 768; }
            __syncthreads();
            #pragma unroll
            for (int i = 0; i < AI; i++)
                gl2lds16(Ak + aoffB + (long)(i * RPO) * lda + kk, &As[i * 2048 + w * 512]);
            f16x8 ball[BK / 32][NJ];
            #pragma unroll
            for (int ks = 0; ks < BK / 32; ks++)
                #pragma unroll
                for (int j = 0; j < NJ; j++) {
                    int r = wn + j * 16 + lr;
                    ball[ks][j] = *(const f16x8*)(Bt + (long)(n0 + r) * ldb + k0 + (ks * 4 + lq) * 8);
                }
            __syncthreads();
            #pragma unroll
            for (int ks = 0; ks < BK / 32; ks++) {
                f16x8 af[4];
                #pragma unroll
                for (int i = 0; i < 4; i++) {
                    int r = wm + i * 16 + lr;
                    int cc = (lq + ks * 4) ^ (r & (CH - 1));
                    af[i] = *(const f16x8*)&As[r * BK + cc * 8];
                }
                #pragma unroll
                for (int i = 0; i < 4; i++)
                    #pragma unroll
                    for (int j = 0; j < NJ; j++)
                        acc[i][j] = __builtin_amdgcn_mfma_f32_16x16x32_f16(af[i], ball[ks][j], acc[i][j], 0, 0, 0);
            }
        }
    } else {
        constexpr int CH  = BK / 8;                  // 16B chunks per row
        constexpr int AI  = TM * BK / 2048;          // staging ops (2048 elems each)
        constexpr int BI  = TN * BK / 2048;
        constexpr int RPO = 2048 / BK;               // rows per staging op
        __shared__ __align__(16) f16 As[TM * BK];
        __shared__ __align__(16) f16 Bs[TN * BK];
        int row0 = t / CH, slot = t % CH;
        int csw = slot ^ (row0 & (CH - 1));
        long aoffB = (long)(m0 + row0) * lda + csw * 8;
        long boffB = (long)(n0 + row0) * ldb + csw * 8;
        for (int k0 = 0; k0 < K; k0 += BK) {
            const f16* Ak = A; int kk = k0;
            if (CAT && k0 >= 768) { Ak = A2; kk = k0 - 768; }
            __syncthreads();
            #pragma unroll
            for (int i = 0; i < AI; i++)
                gl2lds16(Ak + aoffB + (long)(i * RPO) * lda + kk, &As[i * 2048 + w * 512]);
            #pragma unroll
            for (int i = 0; i < BI; i++)
                gl2lds16(Bt + boffB + (long)(i * RPO) * ldb + k0, &Bs[i * 2048 + w * 512]);
            __syncthreads();                         // drains vmcnt before barrier
            #pragma unroll
            for (int ks = 0; ks < BK / 32; ks++) {
                f16x8 af[4], bfr[NJ];
                #pragma unroll
                for (int i = 0; i < 4; i++) {
                    int r = wm + i * 16 + lr;
                    int cc = (lq + ks * 4) ^ (r & (CH - 1));
                    af[i] = *(const f16x8*)&As[r * BK + cc * 8];
                }
                #pragma unroll
                for (int j = 0; j < NJ; j++) {
                    int r = wn + j * 16 + lr;
                    int cc = (lq + ks * 4) ^ (r & (CH - 1));
                    bfr[j] = *(const f16x8*)&Bs[r * BK + cc * 8];
                }
                #pragma unroll
                for (int i = 0; i < 4; i++)
                    #pragma unroll
                    for (int j = 0; j < NJ; j++)
                        acc[i][j] = __builtin_amdgcn_mfma_f32_16x16x32_f16(af[i], bfr[j], acc[i][j], 0, 0, 0);
            }
        }
    }

    int isf = (MODE == OUT_FINAL) ? flags[1] : 0;
    #pragma unroll
    for (int i = 0; i < 4; i++) {
        #pragma unroll
        for (int j = 0; j < NJ; j++) {
            #pragma unroll
            for (int r = 0; r < 4; r++) {
                int gm = m0 + wm + i * 16 + lq * 4 + r;   // C/D: row = quad*4+reg
                int gn = n0 + wn + j * 16 + lr;           //      col = lane&15
                if (MODE == OUT_F16) {
                    if (gm < M && gn < Nc)
                        ((f16*)Cout)[(long)z * sC + (long)gm * ldc + gn] = (f16)acc[i][j][r];
                } else {
                    if (gm < M) {
                        if (gn < Nc) {                     // Nc=75 real cols
                            float v = acc[i][j][r] + bias[gn];
                            // F2 lives in LF at col 1152+gn, ld 1280
                            if (F2c) v += (float)F2c[((long)z * 1000 + gm) * 1280 + 1152 + gn];
                            int oc = (gn < 2) ? gn : gn + 2;   // skip anchor cols 2,3
                            if (gn >= 2) v += ldf(anchors, (long)(gm % 1000) * 77 + oc, isf);
                            stf(Cout, (long)z * sC + (long)gm * 77 + oc, isf, v);
                        } else if (gn < 77) {              // wasted lanes fill anchor cols 2,3
                            int oc = gn - 73;              // 75->2, 76->3
                            stf(Cout, (long)z * sC + (long)gm * 77 + oc, isf,
                                ldf(anchors, (long)(gm % 1000) * 77 + oc, isf));
                        }
                    }
                }
            }
        }
    }
}

extern "C" void kernel_launch(void* const* d_in, const int* in_sizes, int n_in,
                              void* d_out, int out_size, void* d_ws, size_t ws_size,
                              hipStream_t stream)
{
    const void* fv      = d_in[0];
    const void* attn_w  = d_in[1];
    const void* attn_b  = d_in[2];
    const void* cls_w   = d_in[3];
    const void* cls_b   = d_in[4];
    const void* reg_w   = d_in[5];
    const void* reg_b   = d_in[6];
    const void* anchors = d_in[7];
    const int*  x_idx   = (const int*)d_in[10];
    const void* maskp   = d_in[11];
    int xstride = (in_sizes[10] < 768000) ? 12 : 768;   // un-broadcast fallback
    int mstride = (in_sizes[11] < 768000) ? 12 : 768;
    int mwords  = in_sizes[11] / 4;                      // int8 worst case, stay in bounds
    if (mwords > 4096) mwords = 4096;

    char* ws = (char*)d_ws;
    f16*   LF     = (f16*)(ws + OFF_LF);
    f16*   feat   = (f16*)(ws + OFF_FEAT);
    f16*   awT    = (f16*)(ws + OFF_AWT);    // B' rows 0..1023
    f16*   wcT2   = (f16*)(ws + OFF_WCT);    // B' rows 1024..1279 (contiguous after awT)
    float* biasc  = (float*)(ws + OFF_BIAS);
    float* abf32  = (float*)(ws + OFF_AB);
    int*   flags  = (int*)(ws + OFF_FLAG);
    f16*   F1T    = (f16*)(ws + OFF_F1T);

    // front: inline detect + feat gather + weight packing + F1T pad-zero
    front_kernel<<<dim3(2048), dim3(256), 0, stream>>>(
        fv, x_idx, maskp, xstride, mstride, mwords, feat,
        attn_w, cls_w, cls_b, reg_w, reg_b, attn_b, awT, wcT2, biasc, abf32,
        flags, F1T);

    // MERGED GEMM: LF = feat @ [awT | wcT2]  (M=32000, N=1280 = 5x256, K=768)
    // logits -> LF cols 0..1023; F1 -> F1T (transposed, direct); F2 -> LF 1152..1279
    gemm8p_kernel<<<dim3(625), dim3(512), 0, stream>>>(
        feat, 768, awT, 768, LF, 1280, 32000, 125, 5, 12, 0L, 0L, 0L, F1T);
    // softmax-scatter in place (transpose branch eliminated)
    post_kernel<<<dim3(32000), dim3(256), 0, stream>>>(LF, abf32);

    // GEMMS: out = S @ F1 + F2 + bias + anchors  (batched M=1000, N=75(128), K=1024)
    // BG path (B=F1T 8.4 MB L2-hot): A = LF ld 1280 (S in cols 0..1023), A-only LDS,
    // BK=128, TM=64/TN=128 -> 16 mt x 32 batches = 512 blocks, multi-block/CU
    gemm_kernel<OUT_FINAL, false, false, 64, 128, 128, 0, true><<<dim3(1, 16, 32), dim3(256), 0, stream>>>(
        LF, nullptr, 1280, F1T, 1024, d_out, 77, 1000, 75, 1024,
        1280000L, 131072L, 77000L, biasc, anchors, flags, LF);
}

// Round 17
// 281.353 us; speedup vs baseline: 1.0606x; 1.0606x over previous
//
#include <hip/hip_runtime.h>
#include <hip/hip_bf16.h>

typedef _Float16 f16;
typedef _Float16 f16x4 __attribute__((ext_vector_type(4)));
typedef _Float16 f16x8 __attribute__((ext_vector_type(8)));
typedef float    f32x4 __attribute__((ext_vector_type(4)));

static __device__ __forceinline__ float bf2f(__hip_bfloat16 x) { return __bfloat162float(x); }
// dual-dtype float load/store: f32flag=1 -> float*, else bf16*
static __device__ __forceinline__ float ldf(const void* p, long i, int f32flag) {
    return f32flag ? ((const float*)p)[i] : bf2f(((const __hip_bfloat16*)p)[i]);
}
static __device__ __forceinline__ void stf(void* p, long i, int f32flag, float v) {
    if (f32flag) ((float*)p)[i] = v;
    else ((__hip_bfloat16*)p)[i] = __float2bfloat16(v);
}
// async global->LDS, 16B per lane; LDS dest is wave-uniform base + lane*16
static __device__ __forceinline__ void gl2lds16(const f16* g, f16* l) {
    __builtin_amdgcn_global_load_lds(
        (const __attribute__((address_space(1))) unsigned int*)(const void*)g,
        (__attribute__((address_space(3))) unsigned int*)(void*)l, 16, 0, 0);
}

// ---------------- workspace layout (bytes) ----------------
// Re-associated + merged pipeline:
//   LF = feat @ [attn_w^T | Wc1 | Wc2]  (32000 x 1280, ld 1280)
//        cols 0..1023 = logits (999 real), 1024..1151 = F1, 1152..1279 = F2
//   out = softmax-scatter(LF[:, :1024]) @ F1 + F2 + bias + anchors
#define OFF_LF     0L                               // LF: 32000 x 1280 f16
#define SZ_LF      (32000L * 1280 * 2)
#define OFF_FEAT   (OFF_LF + SZ_LF)                 // feat: 32000 x 768 f16
#define SZ_FEAT    (32000L * 768 * 2)
#define OFF_AWT    (OFF_FEAT + SZ_FEAT)             // attn_w^T: 1024 x 768 f16 (rows>=999 zero)
#define SZ_AWT     (1024L * 768 * 2)
#define OFF_WCT    (OFF_AWT + SZ_AWT)               // Wc2^T: 256 x 768 f16 — MUST follow awT
#define SZ_WCT     (256L * 768 * 2)                 // (B' = awT..wcT2 = 1280 contiguous rows)
#define OFF_BIAS   (OFF_WCT + SZ_WCT)               // f32[128]
#define OFF_AB     (OFF_BIAS + 512)                 // attn_b as f32[1024]
#define OFF_FLAG   (OFF_AB + 4096)                  // int flags[2]
#define OFF_F1T    (OFF_FLAG + 64)                  // F1^T per batch: 32 x 128 x 1024 f16
#define SZ_F1T     (32L * 128 * 1024 * 2)
#define NEED_A     (OFF_F1T + SZ_F1T)               // ~141 MB

// ---------------- front: inline detect + build_feat + weight packing (one dispatch) ----------------
// Detection (dtype of fv / format of mask) is recomputed locally by EVERY block from
// the same fixed global sample (deterministic, ~24 KB L2-hot reads). Block 2047
// publishes flags for GEMMS.
// grid 2048: [0,512) feat gather; [512,1280) awT transpose; [1280,2048) wcT2/bias/abf32
__global__ __launch_bounds__(256) void front_kernel(
    const void* __restrict__ fv, const int* __restrict__ x_idx,
    const void* __restrict__ maskp,
    int xstride, int mstride, int mwords, f16* __restrict__ feat,
    const void* __restrict__ attn_w,
    const void* __restrict__ cls_w, const void* __restrict__ cls_b,
    const void* __restrict__ reg_w, const void* __restrict__ reg_b,
    const void* __restrict__ attn_b,
    f16* __restrict__ awT, f16* __restrict__ wcT,
    float* __restrict__ biasc, float* __restrict__ abf32,
    int* __restrict__ flags)
{
    __shared__ int s_cnt, s_bits;
    int bid = blockIdx.x;
    int t = threadIdx.x;
    if (t == 0) { s_cnt = 0; s_bits = 0; }
    __syncthreads();
    {
        const unsigned int* fvw = (const unsigned int*)fv;
        const unsigned int* mw  = (const unsigned int*)maskp;
        int c = 0;
        for (int k = t; k < 2048; k += 256) {
            unsigned int wv = fvw[k];
            unsigned int h0 = wv & 0xffffu, h1 = wv >> 16;
            unsigned int e0 = (h0 >> 7) & 0xffu, e1 = (h1 >> 7) & 0xffu;
            c += (h0 == 0u || (e0 >= 100u && e0 <= 135u)) ? 1 : 0;
            c += (h1 == 0u || (e1 >= 100u && e1 <= 135u)) ? 1 : 0;
        }
        atomicAdd(&s_cnt, c);
        int lb = 0;
        for (int k = t; k < mwords; k += 256) {
            unsigned int wv = mw[k];
            if (wv > 1u) lb |= 1;
            if ((k & 1) && wv != 0u) lb |= 2;
            unsigned int lo = wv & 0xffffu, hi = wv >> 16;
            if (!((lo == 0u || lo == 0x3f80u) && (hi == 0u || hi == 0x3f80u))) lb |= 4;
            if (lo == 0x3f80u) lb |= 8;
        }
        if (lb) atomicOr(&s_bits, lb);
    }
    __syncthreads();
    int db = s_bits, fm;
    if (!(db & 1))      fm = (db & 2) ? 0 : 3;
    else if (!(db & 4)) fm = (db & 8) ? 2 : 4;
    else                fm = 1;
    int isf = (s_cnt < 3900) ? 1 : 0;
    if (bid == 2047 && t == 0) { flags[0] = fm; flags[1] = isf; }   // for GEMMS epilogue

    if (bid < 512) {
        __shared__ f16 sfv[15360];                  // [(c*12+h)*20 + x]
        __shared__ int sx[756];
        __shared__ unsigned char sm[756];
        int b = bid >> 4, n0 = (bid & 15) * 63;
        int rows = min(63, 1000 - n0);
        if (isf) {                                  // f32: 3840 float4
            const float4* src = (const float4*)fv + (long)b * 3840;
            for (int k = t; k < 3840; k += 256) {
                float4 v = src[k];
                f16x4 h; h[0] = (f16)v.x; h[1] = (f16)v.y; h[2] = (f16)v.z; h[3] = (f16)v.w;
                *(f16x4*)&sfv[k * 4] = h;
            }
        } else {                                    // bf16: 1920 uint4
            const uint4* src = (const uint4*)fv + (long)b * 1920;
            for (int k = t; k < 1920; k += 256) {
                uint4 v = src[k];
                unsigned int wv[4] = {v.x, v.y, v.z, v.w};
                f16x8 h;
                #pragma unroll
                for (int j = 0; j < 4; j++) {
                    h[2 * j]     = (f16)__uint_as_float((wv[j] & 0xffffu) << 16);
                    h[2 * j + 1] = (f16)__uint_as_float(wv[j] & 0xffff0000u);
                }
                *(f16x8*)&sfv[k * 8] = h;
            }
        }
        for (int k = t; k < rows * 12; k += 256) {
            int n = k / 12, h = k - n * 12;
            sx[k] = x_idx[(long)(n0 + n) * xstride + h];
            long mb = (long)(n0 + n) * mstride + h;
            int mv;
            if (fm == 0)      mv = ((const int*)maskp)[mb] != 0;
            else if (fm == 1) mv = ((const unsigned char*)maskp)[mb] != 0;
            else if (fm == 2) mv = ((const unsigned short*)maskp)[mb] != 0;
            else if (fm == 3) mv = ((const int*)maskp)[mb * 2] != 0;
            else              mv = ((const unsigned int*)maskp)[mb] != 0;
            sm[k] = (unsigned char)mv;
        }
        __syncthreads();
        for (int q = t; q < rows * 192; q += 256) {
            int n = q / 192, r = q - n * 192;
            int e0 = r * 4;
            f16x4 v;
            #pragma unroll
            for (int j = 0; j < 4; j++) {
                int e = e0 + j;
                int h = e % 12;
                int kk = n * 12 + h;
                v[j] = sm[kk] ? (f16)0.f : sfv[e * 20 + sx[kk]];
            }
            *(f16x4*)(feat + ((long)(b * 1000 + n0 + n)) * 768 + e0) = v;
        }
    } else if (bid < 1280) {
        // attn_w (768 x 999, ld 999) -> awT (1024 x 768, ld 768), rows>=999 zero
        __shared__ f16 tile[32][33];
        int tid = bid - 512;
        int c0 = (tid % 32) * 32, r0 = (tid / 32) * 32;    // c: 0..1023, r: 0..767
        int tx = t & 31, ty = t >> 5;
        #pragma unroll
        for (int i = ty; i < 32; i += 8) {
            int r = r0 + i, c = c0 + tx;
            float v = 0.f;
            if (r < 768 && c < 999) v = ldf(attn_w, (long)r * 999 + c, isf);
            tile[i][tx] = (f16)v;
        }
        __syncthreads();
        #pragma unroll
        for (int i = ty; i < 32; i += 8) {
            int oc = c0 + i, orw = r0 + tx;
            awT[(long)oc * 768 + orw] = tile[tx][i];
        }
    } else {
        // wcT2 [256 x 768]: row c<128 -> Wc[k][c] (att part, W rows 0..767);
        //                   row c>=128 -> Wc[768+k][c-128] (feat part)
        int idx = (bid - 1280) * 256 + t;           // 256*768 = 196608
        if (idx < 256 * 768) {
            int c = idx / 768, k = idx - c * 768;
            int wrow = (c < 128) ? k : 768 + k;
            int wcol = (c < 128) ? c : c - 128;
            float v = 0.f;
            if (wcol < 2)       v = ldf(cls_w, (long)wrow * 2 + wcol, isf);
            else if (wcol < 75) v = ldf(reg_w, (long)wrow * 73 + (wcol - 2), isf);
            wcT[idx] = (f16)v;                       // wcT2[c][k], ld 768
        }
        if (idx < 75)
            biasc[idx] = (idx < 2) ? ldf(cls_b, idx, isf) : ldf(reg_b, idx - 2, isf);
        if (idx < 1024)
            abf32[idx] = (idx < 999) ? ldf(attn_b, idx, isf) : 0.f;
    }
}

// ---------------- post: fused {F1 transpose | softmax-scatter}, LF ld 1280 ----------------
// bid < 1024: transpose LF cols 1024..1151 (F1) -> F1T per batch (128 x 1024).
// bid >= 1024: one LF row (b,i), cols 0..1023: softmax + position-scatter in place.
__global__ __launch_bounds__(256) void post_kernel(
    f16* __restrict__ buf, const float* __restrict__ abf32,
    f16* __restrict__ F1T)
{
    int bid = blockIdx.x;
    int t = threadIdx.x;
    if (bid < 1024) {
        __shared__ f16 tile[64][68];
        int bz = bid >> 5;                          // 32 tiles per batch
        int rq = bid & 31;
        int by = rq & 15, bx = rq >> 4;             // by: r-tile 0..15, bx: c-tile 0..1
        int r0 = by * 64, c0 = bx * 64;
        int tr = t >> 4, tc = (t & 15) * 4;
        const f16* src = buf + (long)bz * 1000 * 1280 + 1024;   // F1 at col 1024
        #pragma unroll
        for (int ii = 0; ii < 4; ii++) {
            int r = r0 + ii * 16 + tr;
            f16x4 v = {(f16)0.f, (f16)0.f, (f16)0.f, (f16)0.f};
            if (r < 1000) v = *(const f16x4*)(src + (long)r * 1280 + c0 + tc);
            *(f16x4*)&tile[ii * 16 + tr][tc] = v;
        }
        __syncthreads();
        f16* dst = F1T + (long)bz * 131072;
        #pragma unroll
        for (int ii = 0; ii < 4; ii++) {
            int d = ii * 16 + tr;
            f16x4 v;
            #pragma unroll
            for (int j = 0; j < 4; j++) v[j] = tile[tc + j][d];
            *(f16x4*)(dst + (long)(c0 + d) * 1024 + r0 + tc) = v;
        }
        return;
    }
    int rid = bid - 1024;
    int i = rid % 1000, b = rid / 1000;
    f16* row = buf + ((long)(b * 1000 + i)) * 1280;
    __shared__ float red[8];
    __shared__ float epv[256];
    int k0 = t * 4;
    f16x4 rv = *(const f16x4*)(row + k0);            // all reads before any write
    float4 ab = *(const float4*)(abf32 + k0);
    float abv[4] = {ab.x, ab.y, ab.z, ab.w};
    float v[4];
    float lmax = -3.4e38f;
    #pragma unroll
    for (int j = 0; j < 4; j++) {
        int k = k0 + j;
        float x = (k < 999) ? (float)rv[j] + abv[j] : -3.4e38f;
        v[j] = x;
        lmax = fmaxf(lmax, x);
    }
    #pragma unroll
    for (int o = 32; o > 0; o >>= 1) lmax = fmaxf(lmax, __shfl_down(lmax, o, 64));
    if ((t & 63) == 0) red[t >> 6] = lmax;
    __syncthreads();
    float gmax = fmaxf(fmaxf(red[0], red[1]), fmaxf(red[2], red[3]));
    float e[4];
    float lsum = 0.f;
    #pragma unroll
    for (int j = 0; j < 4; j++) {
        int k = k0 + j;
        float x = (k < 999) ? __expf(v[j] - gmax) : 0.f;
        e[j] = x;
        lsum += x;
    }
    epv[t] = e[3];
    #pragma unroll
    for (int o = 32; o > 0; o >>= 1) lsum += __shfl_down(lsum, o, 64);
    if ((t & 63) == 0) red[4 + (t >> 6)] = lsum;
    __syncthreads();                                 // also covers epv writes
    float inv = 1.f / (red[4] + red[5] + red[6] + red[7]);
    f16x4 outv;
    if (k0 >= 1000) {                                // tail: all zeros
        #pragma unroll
        for (int j = 0; j < 4; j++) outv[j] = (f16)0.f;
    } else if (k0 + 3 < i) {                         // all p < i: own e's
        #pragma unroll
        for (int j = 0; j < 4; j++) outv[j] = (f16)(e[j] * inv);
    } else if (k0 > i) {                             // all p > i: shift by one
        float ep = epv[t - 1];                       // t>=1 guaranteed (k0>i>=0)
        outv[0] = (f16)(ep * inv);
        #pragma unroll
        for (int j = 1; j < 4; j++) outv[j] = (f16)(e[j - 1] * inv);
    } else {                                         // straddle: i in [k0, k0+3]
        #pragma unroll
        for (int j = 0; j < 4; j++) {
            int p = k0 + j;
            float s = (p == i) ? 0.f : ((p < i) ? e[j] : e[j - 1 < 0 ? 0 : j - 1]);
            if (p > i) s = e[j - 1];                 // p>i implies j>=1 here
            outv[j] = (f16)(s * inv);
        }
    }
    *(f16x4*)(row + k0) = outv;
}

// ---------------- 8-phase 256x256 MFMA GEMM (T2+T3+T4+T5) ----------------
// 512 thr = 8 waves (2M x 4N), per-wave 128x64 out, BK=64, dbuf LDS 128 KiB.
// MERGED GEMM: C = feat @ [awT | wcT2] (N=1280 = 5 tiles), one pass producing
// logits+F1+F2 in LF (ld 1280). Coalesced epilogue (F1T-direct-write regressed
// +21 us in round 16 via scatter stores — keep the separate vectorized transpose).
#define SB8   __builtin_amdgcn_sched_barrier(0)
#define BAR8  __builtin_amdgcn_s_barrier()
#define LGKM0 do { asm volatile("s_waitcnt lgkmcnt(0)" ::: "memory"); __builtin_amdgcn_sched_barrier(0); } while (0)
#define VM4   asm volatile("s_waitcnt vmcnt(4)" ::: "memory")

__global__ __launch_bounds__(512, 2) void gemm8p_kernel(
    const f16* __restrict__ A, int lda,
    const f16* __restrict__ Bt, int ldb,
    f16* __restrict__ C, int ldc,
    int M, int MT, int NT, int KT,
    long sA, long sB, long sC)
{
    __shared__ __align__(16) f16 As[2][16384];
    __shared__ __align__(16) f16 Bs[2][16384];
    int t = threadIdx.x;
    int nwg = gridDim.x;
    int orig = blockIdx.x;
    int xcd = orig & 7, lin = orig >> 3;
    int q8 = nwg >> 3, r8 = nwg & 7;                 // bijective XCD swizzle (m204)
    int wgid = (xcd < r8 ? xcd * (q8 + 1) : r8 * (q8 + 1) + (xcd - r8) * q8) + lin;
    int per_b = MT * NT;
    int bz = wgid / per_b;
    int rem = wgid - bz * per_b;
    int mt = rem / NT, nt = rem - mt * NT;
    int m0 = mt * 256, n0 = nt * 256;
    A  += (long)bz * sA;
    Bt += (long)bz * sB;
    C  += (long)bz * sC;
    int w = t >> 6, lane = t & 63;
    int wm = (w >> 2) * 128, wn = (w & 3) * 64;
    int lr = lane & 15, lq = lane >> 4;
    int row0 = t >> 3, slot = t & 7;
    int csw = slot ^ (row0 & 7);                     // pre-swizzled global source

    f32x4 acc[8][4];
    const f32x4 z4 = {0.f, 0.f, 0.f, 0.f};
    #pragma unroll
    for (int i = 0; i < 8; i++)
        #pragma unroll
        for (int j = 0; j < 4; j++) acc[i][j] = z4;

    f16x8 a_[2][2], b_[4][2];

#define STAGE_A8(kt, h, buf) do { \
    int ktc = (kt) < KT ? (kt) : KT - 1; \
    const f16* gp = A + (long)(m0 + (h) * 128 + row0) * lda + ktc * 64 + csw * 8; \
    gl2lds16(gp,                  &As[buf][(h) * 8192 + w * 512]); \
    gl2lds16(gp + 64 * (long)lda, &As[buf][(h) * 8192 + 4096 + w * 512]); \
} while (0)
#define STAGE_B8(kt, h, buf) do { \
    int ktc = (kt) < KT ? (kt) : KT - 1; \
    const f16* gp = Bt + (long)(n0 + (h) * 128 + row0) * ldb + ktc * 64 + csw * 8; \
    gl2lds16(gp,                  &Bs[buf][(h) * 8192 + w * 512]); \
    gl2lds16(gp + 64 * (long)ldb, &Bs[buf][(h) * 8192 + 4096 + w * 512]); \
} while (0)
#define RD_B8(buf) { \
    _Pragma("unroll") for (int n = 0; n < 4; n++) { \
        int r = wn + n * 16 + lr; int rb = r * 64; int x7 = r & 7; \
        _Pragma("unroll") for (int ks = 0; ks < 2; ks++) { \
            int cc = (lq + ks * 4) ^ x7; \
            b_[n][ks] = *(const f16x8*)&Bs[buf][rb + cc * 8]; } } }
#define RD_A8(q, buf) { \
    _Pragma("unroll") for (int m2 = 0; m2 < 2; m2++) { \
        int r = wm + ((q) * 2 + m2) * 16 + lr; int rb = r * 64; int x7 = r & 7; \
        _Pragma("unroll") for (int ks = 0; ks < 2; ks++) { \
            int cc = (lq + ks * 4) ^ x7; \
            a_[m2][ks] = *(const f16x8*)&As[buf][rb + cc * 8]; } } }
#define MFMA16(q) { \
    __builtin_amdgcn_s_setprio(1); \
    _Pragma("unroll") for (int ks = 0; ks < 2; ks++) \
    _Pragma("unroll") for (int m2 = 0; m2 < 2; m2++) \
    _Pragma("unroll") for (int n = 0; n < 4; n++) \
        acc[(q) * 2 + m2][n] = __builtin_amdgcn_mfma_f32_16x16x32_f16( \
            a_[m2][ks], b_[n][ks], acc[(q) * 2 + m2][n], 0, 0, 0); \
    __builtin_amdgcn_s_setprio(0); }

    // prologue: B(0),A(0) -> buf0; B(1) -> buf1; wait oldest 8, keep B(1) in flight
    STAGE_B8(0, 0, 0); STAGE_B8(0, 1, 0);
    STAGE_A8(0, 0, 0); STAGE_A8(0, 1, 0);
    STAGE_B8(1, 0, 1); STAGE_B8(1, 1, 1);
    VM4;
    BAR8;

    int NIT = KT >> 1;
    for (int it = 0; it < NIT; it++) {
        int t0 = 2 * it, t1 = t0 + 1;
        SB8; RD_B8(0); RD_A8(0, 0); STAGE_A8(t1, 0, 1);
        BAR8; LGKM0; MFMA16(0); BAR8;
        SB8; RD_A8(1, 0); STAGE_A8(t1, 1, 1);
        BAR8; LGKM0; MFMA16(1); BAR8;
        SB8; RD_A8(2, 0); STAGE_B8(t0 + 2, 0, 0);
        BAR8; LGKM0; MFMA16(2); BAR8;
        SB8; RD_A8(3, 0); STAGE_B8(t0 + 2, 1, 0);
        BAR8; LGKM0; MFMA16(3); VM4; BAR8;
        SB8; RD_B8(1); RD_A8(0, 1); STAGE_A8(t0 + 2, 0, 0);
        BAR8; LGKM0; MFMA16(0); BAR8;
        SB8; RD_A8(1, 1); STAGE_A8(t0 + 2, 1, 0);
        BAR8; LGKM0; MFMA16(1); BAR8;
        SB8; RD_A8(2, 1); STAGE_B8(t1 + 2, 0, 1);
        BAR8; LGKM0; MFMA16(2); BAR8;
        SB8; RD_A8(3, 1); STAGE_B8(t1 + 2, 1, 1);
        BAR8; LGKM0; MFMA16(3); VM4; BAR8;
    }

    // epilogue: C/D layout col=lane&15, row=(lane>>4)*4+reg
    #pragma unroll
    for (int m = 0; m < 8; m++)
        #pragma unroll
        for (int n = 0; n < 4; n++)
            #pragma unroll
            for (int r = 0; r < 4; r++) {
                int gm = m0 + wm + m * 16 + lq * 4 + r;
                int gn = n0 + wn + n * 16 + lr;
                if (gm < M) C[(long)gm * ldc + gn] = (f16)acc[m][n][r];
            }
#undef STAGE_A8
#undef STAGE_B8
#undef RD_B8
#undef RD_A8
#undef MFMA16
}

// ---------------- MFMA GEMM (GEMMS: BG path, A-only LDS, fused epilogue) ----------------
enum { OUT_F16 = 0, OUT_FINAL = 1 };

template<int MODE, bool CAT, bool BKM, int TM, int TN, int BK, int SWZ, bool BG>
__global__ __launch_bounds__(256, 2) void gemm_kernel(
    const f16* __restrict__ A, const f16* __restrict__ A2, int lda,
    const f16* __restrict__ Bt, int ldb,
    void* __restrict__ Cout, int ldc,
    int M, int Nc, int K,
    long sA, long sB, long sC,
    const float* __restrict__ bias, const void* __restrict__ anchors,
    const int* __restrict__ flags, const f16* __restrict__ F2c)
{
    int t = threadIdx.x;
    int bx, by, bz;
    bx = blockIdx.x; by = blockIdx.y; bz = blockIdx.z;

    int m0 = by * TM, n0 = bx * TN;
    int z = bz;
    A  += (long)z * sA;
    if (CAT) A2 += (long)z * sA;
    Bt += (long)z * sB;
    int w = t >> 6, lane = t & 63;
    constexpr int NJ = (TM == 128 && TN == 256) ? 8 : ((TN == 256) ? 4 : ((TM == 128) ? 4 : 2));
    int wm = (TM == 128) ? (w & 1) * 64 : 0;
    int wn;
    if constexpr (TM == 128 && TN == 256) wn = (w >> 1) * 128;
    else if constexpr (TN == 256)         wn = w * 64;
    else if constexpr (TM == 128)         wn = (w >> 1) * 64;
    else                                  wn = w * 32;

    int lr = lane & 15, lq = lane >> 4;

    const f32x4 zero4 = {0.f, 0.f, 0.f, 0.f};
    f32x4 acc[4][NJ];
    #pragma unroll
    for (int i = 0; i < 4; i++)
        #pragma unroll
        for (int j = 0; j < NJ; j++) acc[i][j] = zero4;

    if constexpr (BG) {
        // A staged to LDS; B fragments straight from global (B must be L2-hot & row-padded)
        constexpr int CH  = BK / 8;
        constexpr int AI  = TM * BK / 2048;
        constexpr int RPO = 2048 / BK;
        __shared__ __align__(16) f16 As[TM * BK];
        int row0 = t / CH, slot = t % CH;
        int csw = slot ^ (row0 & (CH - 1));
        long aoffB = (long)(m0 + row0) * lda + csw * 8;
        for (int k0 = 0; k0 < K; k0 += BK) {
            const f16* Ak = A; int kk = k0;
            if (CAT && k0 >= 768) { Ak = A2; kk = k0 - 768; }
            __syncthreads();
            #pragma unroll
            for (int i = 0; i < AI; i++)
                gl2lds16(Ak + aoffB + (long)(i * RPO) * lda + kk, &As[i * 2048 + w * 512]);
            f16x8 ball[BK / 32][NJ];
            #pragma unroll
            for (int ks = 0; ks < BK / 32; ks++)
                #pragma unroll
                for (int j = 0; j < NJ; j++) {
                    int r = wn + j * 16 + lr;
                    ball[ks][j] = *(const f16x8*)(Bt + (long)(n0 + r) * ldb + k0 + (ks * 4 + lq) * 8);
                }
            __syncthreads();
            #pragma unroll
            for (int ks = 0; ks < BK / 32; ks++) {
                f16x8 af[4];
                #pragma unroll
                for (int i = 0; i < 4; i++) {
                    int r = wm + i * 16 + lr;
                    int cc = (lq + ks * 4) ^ (r & (CH - 1));
                    af[i] = *(const f16x8*)&As[r * BK + cc * 8];
                }
                #pragma unroll
                for (int i = 0; i < 4; i++)
                    #pragma unroll
                    for (int j = 0; j < NJ; j++)
                        acc[i][j] = __builtin_amdgcn_mfma_f32_16x16x32_f16(af[i], ball[ks][j], acc[i][j], 0, 0, 0);
            }
        }
    } else {
        constexpr int CH  = BK / 8;                  // 16B chunks per row
        constexpr int AI  = TM * BK / 2048;          // staging ops (2048 elems each)
        constexpr int BI  = TN * BK / 2048;
        constexpr int RPO = 2048 / BK;               // rows per staging op
        __shared__ __align__(16) f16 As[TM * BK];
        __shared__ __align__(16) f16 Bs[TN * BK];
        int row0 = t / CH, slot = t % CH;
        int csw = slot ^ (row0 & (CH - 1));
        long aoffB = (long)(m0 + row0) * lda + csw * 8;
        long boffB = (long)(n0 + row0) * ldb + csw * 8;
        for (int k0 = 0; k0 < K; k0 += BK) {
            const f16* Ak = A; int kk = k0;
            if (CAT && k0 >= 768) { Ak = A2; kk = k0 - 768; }
            __syncthreads();
            #pragma unroll
            for (int i = 0; i < AI; i++)
                gl2lds16(Ak + aoffB + (long)(i * RPO) * lda + kk, &As[i * 2048 + w * 512]);
            #pragma unroll
            for (int i = 0; i < BI; i++)
                gl2lds16(Bt + boffB + (long)(i * RPO) * ldb + k0, &Bs[i * 2048 + w * 512]);
            __syncthreads();                         // drains vmcnt before barrier
            #pragma unroll
            for (int ks = 0; ks < BK / 32; ks++) {
                f16x8 af[4], bfr[NJ];
                #pragma unroll
                for (int i = 0; i < 4; i++) {
                    int r = wm + i * 16 + lr;
                    int cc = (lq + ks * 4) ^ (r & (CH - 1));
                    af[i] = *(const f16x8*)&As[r * BK + cc * 8];
                }
                #pragma unroll
                for (int j = 0; j < NJ; j++) {
                    int r = wn + j * 16 + lr;
                    int cc = (lq + ks * 4) ^ (r & (CH - 1));
                    bfr[j] = *(const f16x8*)&Bs[r * BK + cc * 8];
                }
                #pragma unroll
                for (int i = 0; i < 4; i++)
                    #pragma unroll
                    for (int j = 0; j < NJ; j++)
                        acc[i][j] = __builtin_amdgcn_mfma_f32_16x16x32_f16(af[i], bfr[j], acc[i][j], 0, 0, 0);
            }
        }
    }

    int isf = (MODE == OUT_FINAL) ? flags[1] : 0;
    #pragma unroll
    for (int i = 0; i < 4; i++) {
        #pragma unroll
        for (int j = 0; j < NJ; j++) {
            #pragma unroll
            for (int r = 0; r < 4; r++) {
                int gm = m0 + wm + i * 16 + lq * 4 + r;   // C/D: row = quad*4+reg
                int gn = n0 + wn + j * 16 + lr;           //      col = lane&15
                if (MODE == OUT_F16) {
                    if (gm < M && gn < Nc)
                        ((f16*)Cout)[(long)z * sC + (long)gm * ldc + gn] = (f16)acc[i][j][r];
                } else {
                    if (gm < M) {
                        if (gn < Nc) {                     // Nc=75 real cols
                            float v = acc[i][j][r] + bias[gn];
                            // F2 lives in LF at col 1152+gn, ld 1280
                            if (F2c) v += (float)F2c[((long)z * 1000 + gm) * 1280 + 1152 + gn];
                            int oc = (gn < 2) ? gn : gn + 2;   // skip anchor cols 2,3
                            if (gn >= 2) v += ldf(anchors, (long)(gm % 1000) * 77 + oc, isf);
                            stf(Cout, (long)z * sC + (long)gm * 77 + oc, isf, v);
                        } else if (gn < 77) {              // wasted lanes fill anchor cols 2,3
                            int oc = gn - 73;              // 75->2, 76->3
                            stf(Cout, (long)z * sC + (long)gm * 77 + oc, isf,
                                ldf(anchors, (long)(gm % 1000) * 77 + oc, isf));
                        }
                    }
                }
            }
        }
    }
}

extern "C" void kernel_launch(void* const* d_in, const int* in_sizes, int n_in,
                              void* d_out, int out_size, void* d_ws, size_t ws_size,
                              hipStream_t stream)
{
    const void* fv      = d_in[0];
    const void* attn_w  = d_in[1];
    const void* attn_b  = d_in[2];
    const void* cls_w   = d_in[3];
    const void* cls_b   = d_in[4];
    const void* reg_w   = d_in[5];
    const void* reg_b   = d_in[6];
    const void* anchors = d_in[7];
    const int*  x_idx   = (const int*)d_in[10];
    const void* maskp   = d_in[11];
    int xstride = (in_sizes[10] < 768000) ? 12 : 768;   // un-broadcast fallback
    int mstride = (in_sizes[11] < 768000) ? 12 : 768;
    int mwords  = in_sizes[11] / 4;                      // int8 worst case, stay in bounds
    if (mwords > 4096) mwords = 4096;

    char* ws = (char*)d_ws;
    f16*   LF     = (f16*)(ws + OFF_LF);
    f16*   feat   = (f16*)(ws + OFF_FEAT);
    f16*   awT    = (f16*)(ws + OFF_AWT);    // B' rows 0..1023
    f16*   wcT2   = (f16*)(ws + OFF_WCT);    // B' rows 1024..1279 (contiguous after awT)
    float* biasc  = (float*)(ws + OFF_BIAS);
    float* abf32  = (float*)(ws + OFF_AB);
    int*   flags  = (int*)(ws + OFF_FLAG);
    f16*   F1T    = (f16*)(ws + OFF_F1T);

    // front: inline detect (per-block, deterministic) + feat gather + weight packing
    front_kernel<<<dim3(2048), dim3(256), 0, stream>>>(
        fv, x_idx, maskp, xstride, mstride, mwords, feat,
        attn_w, cls_w, cls_b, reg_w, reg_b, attn_b, awT, wcT2, biasc, abf32, flags);

    // MERGED GEMM: LF = feat @ [awT | wcT2]  (M=32000, N=1280 = 5x256, K=768)
    // One pass produces logits (cols 0..1023) + F1 (1024..1151) + F2 (1152..1279).
    // 8-phase 256^2, 125x5 = 625 blocks x 512 thr.
    gemm8p_kernel<<<dim3(625), dim3(512), 0, stream>>>(
        feat, 768, awT, 768, LF, 1280, 32000, 125, 5, 12, 0L, 0L, 0L);
    // fused: F1 transpose (1024 blocks) + softmax-scatter (32000 blocks), LF ld 1280
    post_kernel<<<dim3(1024 + 32000), dim3(256), 0, stream>>>(LF, abf32, F1T);

    // GEMMS: out = S @ F1 + F2 + bias + anchors  (batched M=1000, N=75(128), K=1024)
    // BG path (B=F1T 8.4 MB L2-hot): A = LF ld 1280 (S in cols 0..1023), A-only LDS,
    // BK=128, TM=64/TN=128 -> 16 mt x 32 batches = 512 blocks, multi-block/CU
    gemm_kernel<OUT_FINAL, false, false, 64, 128, 128, 0, true><<<dim3(1, 16, 32), dim3(256), 0, stream>>>(
        LF, nullptr, 1280, F1T, 1024, d_out, 77, 1000, 75, 1024,
        1280000L, 131072L, 77000L, biasc, anchors, flags, LF);
}